// Round 2
// baseline (200.315 us; speedup 1.0000x reference)
//
#include <hip/hip_runtime.h>

typedef short bf16x8 __attribute__((ext_vector_type(8)));
typedef float f32x4 __attribute__((ext_vector_type(4)));

#define MFMA(a, b, c) __builtin_amdgcn_mfma_f32_16x16x32_bf16((a), (b), (c), 0, 0, 0)

// hardware packed f32->bf16 (RNE): 1 instr replaces ~6 integer-ALU ops
__device__ __forceinline__ unsigned cvtpk(float a, float b) {
    unsigned r;
    asm("v_cvt_pk_bf16_f32 %0, %1, %2" : "=v"(r) : "v"(a), "v"(b));
    return r;
}

// async global->LDS, 16B per lane; LDS dest = wave-uniform base + lane*16
__device__ __forceinline__ void gload16(const void* g, void* l) {
    __builtin_amdgcn_global_load_lds(
        (const __attribute__((address_space(1))) unsigned*)g,
        (__attribute__((address_space(3))) unsigned*)l, 16, 0, 0);
}

// ---------------------------------------------------------------------------
// f32 -> bf16 convert (x: blocks 0..4095; W0..W3: 256 blocks each)
// ---------------------------------------------------------------------------
__global__ __launch_bounds__(256) void cvt_kernel(
    const float* __restrict__ x,
    const float* __restrict__ w0, const float* __restrict__ w1,
    const float* __restrict__ w2, const float* __restrict__ w3,
    unsigned short* __restrict__ xd,
    unsigned short* __restrict__ d0, unsigned short* __restrict__ d1,
    unsigned short* __restrict__ d2, unsigned short* __restrict__ d3)
{
    int bid = blockIdx.x;
    const float* src;
    unsigned short* dst;
    int off;
    if (bid < 4096) { src = x; dst = xd; off = bid; }
    else {
        int s = (bid - 4096) >> 8;
        src = s == 0 ? w0 : (s == 1 ? w1 : (s == 2 ? w2 : w3));
        dst = s == 0 ? d0 : (s == 1 ? d1 : (s == 2 ? d2 : d3));
        off = (bid - 4096) & 255;
    }
    size_t i = ((size_t)off * 256 + threadIdx.x) * 4;
    float4 v = *(const float4*)(src + i);
    uint2 pk;
    pk.x = cvtpk(v.x, v.y);
    pk.y = cvtpk(v.z, v.w);
    *(uint2*)(dst + i) = pk;
}

// ---------------------------------------------------------------------------
// 128x128 GEMM tile core: C = A[M,512] * W[512,512]^T (bf16, K-contiguous).
// Staging via global_load_lds (linear LDS dest, pre-swizzled global source):
// LDS[row][slot] = A[row][slot ^ (row&7)] — same invariant as the reg-staged
// version, so the ds_read fragment path is unchanged.
// ---------------------------------------------------------------------------
__device__ __forceinline__ void gemm128_core(
    const unsigned short* __restrict__ A, const unsigned short* __restrict__ W,
    int m0, int n0, int tid, unsigned short* sA, unsigned short* sB,
    f32x4 acc[4][4])
{
    const int lane = tid & 63, wid = tid >> 6;
    const int quad = lane >> 4, l15 = lane & 15;
    const int wm = wid >> 1, wn = wid & 1;

    // source swizzle for gload_lds: lane l covers dest byte chunk*1024+l*16
    // -> row = chunk*8 + (l>>3), slot = l&7, so src kc = (l&7)^(l>>3)
    const int gl_r = lane >> 3;               // 0..7 (== row&7)
    const int gl_kc = (lane & 7) ^ gl_r;      // source k-chunk

    #pragma unroll
    for (int i = 0; i < 4; i++)
        #pragma unroll
        for (int j = 0; j < 4; j++) {
            f32x4 z = {0.f, 0.f, 0.f, 0.f};
            acc[i][j] = z;
        }

    for (int k0 = 0; k0 < 512; k0 += 64) {
        #pragma unroll
        for (int p = 0; p < 4; p++) {
            int chunk = wid * 4 + p;          // 0..15
            int row = chunk * 8 + gl_r;       // 0..127
            gload16(A + (size_t)(m0 + row) * 512 + k0 + gl_kc * 8,
                    (char*)sA + chunk * 1024);
            gload16(W + (size_t)(n0 + row) * 512 + k0 + gl_kc * 8,
                    (char*)sB + chunk * 1024);
        }
        __syncthreads();
        #pragma unroll
        for (int ks = 0; ks < 2; ks++) {
            bf16x8 af[4], bfr[4];
            #pragma unroll
            for (int i = 0; i < 4; i++) {
                int row = wm * 64 + i * 16 + l15;
                int kc = ks * 4 + quad;
                af[i] = *(const bf16x8*)((const char*)sA + row * 128 + ((kc ^ (row & 7)) << 4));
            }
            #pragma unroll
            for (int j = 0; j < 4; j++) {
                int row = wn * 64 + j * 16 + l15;
                int kc = ks * 4 + quad;
                bfr[j] = *(const bf16x8*)((const char*)sB + row * 128 + ((kc ^ (row & 7)) << 4));
            }
            #pragma unroll
            for (int i = 0; i < 4; i++)
                #pragma unroll
                for (int j = 0; j < 4; j++)
                    acc[i][j] = MFMA(af[i], bfr[j], acc[i][j]);
        }
        __syncthreads();
    }
}

// ---------------------------------------------------------------------------
// QKV projection: grid (64, 12); sel = y>>2 (0=q,1=k,2=v), n-tile = y&3.
// q: head-major [B,H,T,64], PRE-SCALED by 0.125*log2(e) (softmax fold).
// k: head-major [B,H,T,64]. v: transposed [B,H,64,T].
// ---------------------------------------------------------------------------
__global__ __launch_bounds__(256) void qkv_kernel(
    const unsigned short* __restrict__ x,
    const unsigned short* __restrict__ Wq, const float* __restrict__ bq,
    const unsigned short* __restrict__ Wk, const float* __restrict__ bk,
    const unsigned short* __restrict__ Wv, const float* __restrict__ bv,
    unsigned short* __restrict__ qo, unsigned short* __restrict__ ko,
    unsigned short* __restrict__ vo)
{
    __shared__ unsigned short sA[128 * 64];
    __shared__ unsigned short sB[128 * 64];
    const int tid = threadIdx.x;
    const int by = blockIdx.y;
    const int sel = by >> 2;
    const int n0 = (by & 3) * 128;
    const int m0 = blockIdx.x * 128;
    const unsigned short* W = sel == 0 ? Wq : (sel == 1 ? Wk : Wv);
    const float* bias = sel == 0 ? bq : (sel == 1 ? bk : bv);

    f32x4 acc[4][4];
    gemm128_core(x, W, m0, n0, tid, sA, sB, acc);

    const int lane = tid & 63, wid = tid >> 6;
    const int quad = lane >> 4, l15 = lane & 15;
    const int wm = wid >> 1, wn = wid & 1;
    float bv4[4];
    #pragma unroll
    for (int j = 0; j < 4; j++) bv4[j] = bias[n0 + wn * 64 + j * 16 + l15];

    if (sel == 2) {
        // V^T: [B,H,64,T]
        #pragma unroll
        for (int i = 0; i < 4; i++) {
            #pragma unroll
            for (int j = 0; j < 4; j++) {
                int n = n0 + wn * 64 + j * 16 + l15;
                int h = n >> 6, d = n & 63;
                int m = m0 + wm * 64 + i * 16 + quad * 4;
                int b = m >> 12, t = m & 4095;
                uint2 pk;
                pk.x = cvtpk(acc[i][j][0] + bv4[j], acc[i][j][1] + bv4[j]);
                pk.y = cvtpk(acc[i][j][2] + bv4[j], acc[i][j][3] + bv4[j]);
                *(uint2*)(vo + ((size_t)(b * 8 + h) * 64 + d) * 4096 + t) = pk;
            }
        }
    } else {
        const float SC = (sel == 0) ? 0.125f * 1.44269504088896f : 1.0f;
        unsigned short* dst = sel == 0 ? qo : ko;
        #pragma unroll
        for (int i = 0; i < 4; i++) {
            #pragma unroll
            for (int j = 0; j < 4; j++) {
                int n = n0 + wn * 64 + j * 16 + l15;
                int h = n >> 6, d = n & 63;
                int m = m0 + wm * 64 + i * 16 + quad * 4;
                int b = m >> 12, t = m & 4095;
                size_t base2 = ((size_t)(b * 8 + h) * 4096 + t) * 64 + d;
                unsigned p01 = cvtpk((acc[i][j][0] + bv4[j]) * SC,
                                     (acc[i][j][1] + bv4[j]) * SC);
                unsigned p23 = cvtpk((acc[i][j][2] + bv4[j]) * SC,
                                     (acc[i][j][3] + bv4[j]) * SC);
                dst[base2]       = (unsigned short)p01;
                dst[base2 + 64]  = (unsigned short)(p01 >> 16);
                dst[base2 + 128] = (unsigned short)p23;
                dst[base2 + 192] = (unsigned short)(p23 >> 16);
            }
        }
    }
}

// ---------------------------------------------------------------------------
// Flash attention, key-split. grid (32 q-tiles, 16 b*h), 512 threads = 2
// key-groups x 4 sub-waves; sub-wave owns 32 q rows. Q pre-scaled so
// p = exp2(s) directly. l-sums via ones-MFMA (column sums, no shuffles).
// S/PV interleaved at half-tile granularity: rb{0,1} feed PV ks2=0,
// rb{2,3} feed PV ks2=1 (sP traffic is wave-local; lgkmcnt orders it).
// ---------------------------------------------------------------------------
__global__ __launch_bounds__(512, 4) void attn_kernel(
    const unsigned short* __restrict__ qg, const unsigned short* __restrict__ kg,
    const unsigned short* __restrict__ vtg, unsigned short* __restrict__ og)
{
    __shared__ unsigned char smem[65536];

    const int tid = threadIdx.x;
    const int lane = tid & 63;
    const int w = tid >> 6;          // wave 0..7
    const int g = tid >> 8;          // key-group 0,1
    const int gt = tid & 255;
    const int sw = w & 3;            // sub-wave in group
    const int quad = lane >> 4, l15 = lane & 15;
    const int bh = blockIdx.y;
    const size_t base = (size_t)bh * 4096 * 64;
    const unsigned short* Q = qg + base;
    const unsigned short* K = kg + base;
    const unsigned short* VT = vtg + base;   // [64 d][4096 t]
    const int qt0 = blockIdx.x * 128;

    unsigned short* sK  = (unsigned short*)(smem + g * 8192);          // [64 key][64 d]
    unsigned short* sVt = (unsigned short*)(smem + 16384 + g * 8192);  // [64 d][64 key]
    unsigned char*  sP  = smem + 32768 + w * 4096;                     // 32 q x 128B

    // Q fragments (B-operand of K.Q^T), persistent; Q pre-scaled in qkv
    bf16x8 qf[2][2];
    #pragma unroll
    for (int cb = 0; cb < 2; cb++) {
        int q = qt0 + sw * 32 + cb * 16 + l15;
        #pragma unroll
        for (int ks = 0; ks < 2; ks++)
            qf[cb][ks] = *(const bf16x8*)(Q + (size_t)q * 64 + ks * 32 + quad * 8);
    }

    f32x4 ot[4][2];
    #pragma unroll
    for (int i = 0; i < 4; i++)
        #pragma unroll
        for (int cb = 0; cb < 2; cb++) {
            f32x4 z = {0.f, 0.f, 0.f, 0.f};
            ot[i][cb] = z;
        }
    f32x4 ls[2];
    {
        f32x4 z = {0.f, 0.f, 0.f, 0.f};
        ls[0] = z; ls[1] = z;
    }
    const short one_b = (short)0x3F80;  // bf16 1.0
    const bf16x8 ones = {one_b, one_b, one_b, one_b, one_b, one_b, one_b, one_b};

    const int c0 = gt, c1 = gt + 256;
    const int r0 = c0 >> 3, kc0 = c0 & 7;
    const int r1 = c1 >> 3, kc1 = c1 & 7;

    // preload tile g*64
    uint4 kr0, kr1, vr0, vr1;
    {
        int kb = g * 64;
        kr0 = *(const uint4*)(K + (size_t)(kb + r0) * 64 + kc0 * 8);
        kr1 = *(const uint4*)(K + (size_t)(kb + r1) * 64 + kc1 * 8);
        vr0 = *(const uint4*)(VT + (size_t)r0 * 4096 + kb + kc0 * 8);
        vr1 = *(const uint4*)(VT + (size_t)r1 * 4096 + kb + kc1 * 8);
    }

    for (int it = 0; it < 32; it++) {
        // stage regs -> LDS
        *(uint4*)((char*)sK + r0 * 128 + ((kc0 ^ (r0 & 7)) << 4)) = kr0;
        *(uint4*)((char*)sK + r1 * 128 + ((kc1 ^ (r1 & 7)) << 4)) = kr1;
        *(uint4*)((char*)sVt + r0 * 128 + ((kc0 ^ (r0 & 7)) << 4)) = vr0;
        *(uint4*)((char*)sVt + r1 * 128 + ((kc1 ^ (r1 & 7)) << 4)) = vr1;
        __syncthreads();

        // deep prefetch of next tile into registers
        {
            int itn = (it < 31) ? it + 1 : it;
            int kbn = (2 * itn + g) * 64;
            kr0 = *(const uint4*)(K + (size_t)(kbn + r0) * 64 + kc0 * 8);
            kr1 = *(const uint4*)(K + (size_t)(kbn + r1) * 64 + kc1 * 8);
            vr0 = *(const uint4*)(VT + (size_t)r0 * 4096 + kbn + kc0 * 8);
            vr1 = *(const uint4*)(VT + (size_t)r1 * 4096 + kbn + kc1 * 8);
        }

        #pragma unroll
        for (int half = 0; half < 2; half++) {
            // S-phase half: rb = half*2, half*2+1 -> sP slots kp = half*4..+3
            #pragma unroll
            for (int rb2 = 0; rb2 < 2; rb2++) {
                int rb = half * 2 + rb2;
                int row = rb * 16 + l15;
                f32x4 s0 = {0.f, 0.f, 0.f, 0.f};
                f32x4 s1 = {0.f, 0.f, 0.f, 0.f};
                __builtin_amdgcn_s_setprio(1);
                #pragma unroll
                for (int ks = 0; ks < 2; ks++) {
                    int kc = ks * 4 + quad;
                    bf16x8 ka = *(const bf16x8*)((const char*)sK + row * 128 + ((kc ^ (row & 7)) << 4));
                    s0 = MFMA(ka, qf[0][ks], s0);
                    s1 = MFMA(ka, qf[1][ks], s1);
                }
                __builtin_amdgcn_s_setprio(0);
                // keys rb*16 + quad*4 + {0..3} -> kp = rb*2 + quad>>1, sub quad&1
                int poff = (((rb * 2 + (quad >> 1)) ^ (l15 & 7)) << 4) + ((quad & 1) << 3);
                {
                    uint2 pk;
                    pk.x = cvtpk(__builtin_amdgcn_exp2f(s0[0]),
                                 __builtin_amdgcn_exp2f(s0[1]));
                    pk.y = cvtpk(__builtin_amdgcn_exp2f(s0[2]),
                                 __builtin_amdgcn_exp2f(s0[3]));
                    *(uint2*)(sP + l15 * 128 + poff) = pk;
                }
                {
                    uint2 pk;
                    pk.x = cvtpk(__builtin_amdgcn_exp2f(s1[0]),
                                 __builtin_amdgcn_exp2f(s1[1]));
                    pk.y = cvtpk(__builtin_amdgcn_exp2f(s1[2]),
                                 __builtin_amdgcn_exp2f(s1[3]));
                    *(uint2*)(sP + (16 + l15) * 128 + poff) = pk;
                }
            }
            // wave-local P write -> read ordering
            __asm__ __volatile__("s_waitcnt lgkmcnt(0)" ::: "memory");

            // PV half: ks2 = half reads sP slots kp = half*4..+3
            {
                int ks2 = half;
                int pslot = (((ks2 * 4 + quad) ^ (l15 & 7)) << 4);
                bf16x8 pfr0 = *(const bf16x8*)(sP + l15 * 128 + pslot);
                bf16x8 pfr1 = *(const bf16x8*)(sP + (16 + l15) * 128 + pslot);
                __builtin_amdgcn_s_setprio(1);
                ls[0] = MFMA(ones, pfr0, ls[0]);
                ls[1] = MFMA(ones, pfr1, ls[1]);
                #pragma unroll
                for (int rbd = 0; rbd < 4; rbd++) {
                    int row = rbd * 16 + l15;
                    int kc = ks2 * 4 + quad;
                    bf16x8 vf = *(const bf16x8*)((const char*)sVt + row * 128 + ((kc ^ (row & 7)) << 4));
                    ot[rbd][0] = MFMA(vf, pfr0, ot[rbd][0]);
                    ot[rbd][1] = MFMA(vf, pfr1, ot[rbd][1]);
                }
                __builtin_amdgcn_s_setprio(0);
            }
        }
        __syncthreads();
    }

    // combine group partials via LDS (pure sums: fixed m=0 softmax)
    float* oc = (float*)(smem + 32768);    // [128 q][64 d] f32, swizzled (32KB)
    float* lc = (float*)smem;              // 128 floats
    if (g == 1) {
        #pragma unroll
        for (int cb = 0; cb < 2; cb++) {
            int qb = sw * 32 + cb * 16 + l15;
            if (quad == 0) lc[qb] = ls[cb][0];
            #pragma unroll
            for (int rbd = 0; rbd < 4; rbd++) {
                int dc = rbd * 4 + quad;
                *(f32x4*)((char*)oc + qb * 256 + ((dc ^ (qb & 15)) << 4)) = ot[rbd][cb];
            }
        }
    }
    __syncthreads();
    if (g == 0) {
        const int b = bh >> 3, h = bh & 7;
        #pragma unroll
        for (int cb = 0; cb < 2; cb++) {
            int qb = sw * 32 + cb * 16 + l15;
            float inv = 1.f / (ls[cb][0] + lc[qb]);
            int q = qt0 + qb;
            #pragma unroll
            for (int rbd = 0; rbd < 4; rbd++) {
                int dc = rbd * 4 + quad;
                f32x4 o2 = *(const f32x4*)((char*)oc + qb * 256 + ((dc ^ (qb & 15)) << 4));
                uint2 pk;
                pk.x = cvtpk((ot[rbd][cb][0] + o2[0]) * inv,
                             (ot[rbd][cb][1] + o2[1]) * inv);
                pk.y = cvtpk((ot[rbd][cb][2] + o2[2]) * inv,
                             (ot[rbd][cb][3] + o2[3]) * inv);
                *(uint2*)(og + ((size_t)(b * 4096 + q) * 512 + h * 64 + rbd * 16 + quad * 4)) = pk;
            }
        }
    }
}

// ---------------------------------------------------------------------------
// Output projection: out = attn[8192,512] @ Wo^T + bo -> float32 out
// ---------------------------------------------------------------------------
__global__ __launch_bounds__(256) void out_kernel(
    const unsigned short* __restrict__ attn,
    const unsigned short* __restrict__ Wo, const float* __restrict__ bo,
    float* __restrict__ out)
{
    __shared__ unsigned short sA[128 * 64];
    __shared__ unsigned short sB[128 * 64];
    const int tid = threadIdx.x;
    const int m0 = blockIdx.x * 128;
    const int n0 = blockIdx.y * 128;

    f32x4 acc[4][4];
    gemm128_core(attn, Wo, m0, n0, tid, sA, sB, acc);

    const int lane = tid & 63, wid = tid >> 6;
    const int quad = lane >> 4, l15 = lane & 15;
    const int wm = wid >> 1, wn = wid & 1;
    float bv4[4];
    #pragma unroll
    for (int j = 0; j < 4; j++) bv4[j] = bo[n0 + wn * 64 + j * 16 + l15];
    #pragma unroll
    for (int i = 0; i < 4; i++) {
        #pragma unroll
        for (int j = 0; j < 4; j++) {
            int n = n0 + wn * 64 + j * 16 + l15;
            #pragma unroll
            for (int r = 0; r < 4; r++) {
                int m = m0 + wm * 64 + i * 16 + quad * 4 + r;
                out[(size_t)m * 512 + n] = acc[i][j][r] + bv4[j];
            }
        }
    }
}

extern "C" void kernel_launch(void* const* d_in, const int* in_sizes, int n_in,
                              void* d_out, int out_size, void* d_ws, size_t ws_size,
                              hipStream_t stream) {
    const float* x  = (const float*)d_in[0];
    const float* Wq = (const float*)d_in[1];
    const float* bq = (const float*)d_in[2];
    const float* Wk = (const float*)d_in[3];
    const float* bk = (const float*)d_in[4];
    const float* Wv = (const float*)d_in[5];
    const float* bv = (const float*)d_in[6];
    const float* Wo = (const float*)d_in[7];
    const float* bo = (const float*)d_in[8];
    unsigned short* ws = (unsigned short*)d_ws;

    const size_t NTOK = (size_t)2 * 4096 * 512;
    const size_t WSZ = (size_t)512 * 512;
    unsigned short* xb  = ws;
    unsigned short* Wqb = ws + NTOK;
    unsigned short* Wkb = Wqb + WSZ;
    unsigned short* Wvb = Wkb + WSZ;
    unsigned short* Wob = Wvb + WSZ;
    unsigned short* q_ws = Wob + WSZ;   // [B,H,T,64] (pre-scaled)
    unsigned short* k_ws = q_ws + NTOK; // [B,H,T,64]
    unsigned short* v_ws = k_ws + NTOK; // [B,H,64,T]  (V^T)
    unsigned short* a_ws = v_ws + NTOK; // [B,T,512]

    cvt_kernel<<<5120, 256, 0, stream>>>(x, Wq, Wk, Wv, Wo, xb, Wqb, Wkb, Wvb, Wob);
    qkv_kernel<<<dim3(64, 12), 256, 0, stream>>>(xb, Wqb, bq, Wkb, bk, Wvb, bv,
                                                 q_ws, k_ws, v_ws);
    attn_kernel<<<dim3(32, 16), 512, 0, stream>>>(q_ws, k_ws, v_ws, a_ws);
    out_kernel<<<dim3(64, 4), 256, 0, stream>>>(a_ws, Wob, bo,
                                                (float*)d_out);
}

// Round 4
// 194.531 us; speedup vs baseline: 1.0297x; 1.0297x over previous
//
#include <hip/hip_runtime.h>

typedef short bf16x8 __attribute__((ext_vector_type(8)));
typedef float f32x4 __attribute__((ext_vector_type(4)));
typedef unsigned u32x2 __attribute__((ext_vector_type(2)));
typedef unsigned u32x4 __attribute__((ext_vector_type(4)));

#define MFMA(a, b, c) __builtin_amdgcn_mfma_f32_16x16x32_bf16((a), (b), (c), 0, 0, 0)

// hardware packed f32->bf16 (RNE): 1 instr replaces ~6 integer-ALU ops
__device__ __forceinline__ unsigned cvtpk(float a, float b) {
    unsigned r;
    asm("v_cvt_pk_bf16_f32 %0, %1, %2" : "=v"(r) : "v"(a), "v"(b));
    return r;
}

// async global->LDS, 16B per lane; LDS dest = wave-uniform base + lane*16
__device__ __forceinline__ void gload16(const void* g, void* l) {
    __builtin_amdgcn_global_load_lds(
        (const __attribute__((address_space(1))) unsigned*)g,
        (__attribute__((address_space(3))) unsigned*)l, 16, 0, 0);
}

// ---------------------------------------------------------------------------
// f32 -> bf16 convert (x: blocks 0..4095; W0..W3: 256 blocks each)
// ---------------------------------------------------------------------------
__global__ __launch_bounds__(256) void cvt_kernel(
    const float* __restrict__ x,
    const float* __restrict__ w0, const float* __restrict__ w1,
    const float* __restrict__ w2, const float* __restrict__ w3,
    unsigned short* __restrict__ xd,
    unsigned short* __restrict__ d0, unsigned short* __restrict__ d1,
    unsigned short* __restrict__ d2, unsigned short* __restrict__ d3)
{
    int bid = blockIdx.x;
    const float* src;
    unsigned short* dst;
    int off;
    if (bid < 4096) { src = x; dst = xd; off = bid; }
    else {
        int s = (bid - 4096) >> 8;
        src = s == 0 ? w0 : (s == 1 ? w1 : (s == 2 ? w2 : w3));
        dst = s == 0 ? d0 : (s == 1 ? d1 : (s == 2 ? d2 : d3));
        off = (bid - 4096) & 255;
    }
    size_t i = ((size_t)off * 256 + threadIdx.x) * 4;
    float4 v = *(const float4*)(src + i);
    uint2 pk;
    pk.x = cvtpk(v.x, v.y);
    pk.y = cvtpk(v.z, v.w);
    *(uint2*)(dst + i) = pk;
}

// ---------------------------------------------------------------------------
// 128x128 GEMM tile core: C = A[M,512] * W[512,512]^T (bf16, K-contiguous).
// Staging via global_load_lds (linear LDS dest, pre-swizzled global source):
// LDS[row][slot] = A[row][slot ^ (row&7)].
// ---------------------------------------------------------------------------
__device__ __forceinline__ void gemm128_core(
    const unsigned short* __restrict__ A, const unsigned short* __restrict__ W,
    int m0, int n0, int tid, unsigned short* sA, unsigned short* sB,
    f32x4 acc[4][4])
{
    const int lane = tid & 63, wid = tid >> 6;
    const int quad = lane >> 4, l15 = lane & 15;
    const int wm = wid >> 1, wn = wid & 1;

    // source swizzle for gload_lds: lane l covers dest byte chunk*1024+l*16
    // -> row = chunk*8 + (l>>3), slot = l&7, so src kc = (l&7)^(l>>3)
    const int gl_r = lane >> 3;               // 0..7 (== row&7)
    const int gl_kc = (lane & 7) ^ gl_r;      // source k-chunk

    #pragma unroll
    for (int i = 0; i < 4; i++)
        #pragma unroll
        for (int j = 0; j < 4; j++) {
            f32x4 z = {0.f, 0.f, 0.f, 0.f};
            acc[i][j] = z;
        }

    for (int k0 = 0; k0 < 512; k0 += 64) {
        #pragma unroll
        for (int p = 0; p < 4; p++) {
            int chunk = wid * 4 + p;          // 0..15
            int row = chunk * 8 + gl_r;       // 0..127
            gload16(A + (size_t)(m0 + row) * 512 + k0 + gl_kc * 8,
                    (char*)sA + chunk * 1024);
            gload16(W + (size_t)(n0 + row) * 512 + k0 + gl_kc * 8,
                    (char*)sB + chunk * 1024);
        }
        __syncthreads();
        #pragma unroll
        for (int ks = 0; ks < 2; ks++) {
            bf16x8 af[4], bfr[4];
            #pragma unroll
            for (int i = 0; i < 4; i++) {
                int row = wm * 64 + i * 16 + l15;
                int kc = ks * 4 + quad;
                af[i] = *(const bf16x8*)((const char*)sA + row * 128 + ((kc ^ (row & 7)) << 4));
            }
            #pragma unroll
            for (int j = 0; j < 4; j++) {
                int row = wn * 64 + j * 16 + l15;
                int kc = ks * 4 + quad;
                bfr[j] = *(const bf16x8*)((const char*)sB + row * 128 + ((kc ^ (row & 7)) << 4));
            }
            #pragma unroll
            for (int i = 0; i < 4; i++)
                #pragma unroll
                for (int j = 0; j < 4; j++)
                    acc[i][j] = MFMA(af[i], bfr[j], acc[i][j]);
        }
        __syncthreads();
    }
}

// ---------------------------------------------------------------------------
// QKV projection: grid (64, 12); sel = y>>2 (0=q,1=k,2=v), n-tile = y&3.
// q: head-major [B,H,T,64], PRE-SCALED by 0.125*log2(e) (softmax fold).
// k: head-major [B,H,T,64]. v: transposed [B,H,64,T].
// ---------------------------------------------------------------------------
__global__ __launch_bounds__(256) void qkv_kernel(
    const unsigned short* __restrict__ x,
    const unsigned short* __restrict__ Wq, const float* __restrict__ bq,
    const unsigned short* __restrict__ Wk, const float* __restrict__ bk,
    const unsigned short* __restrict__ Wv, const float* __restrict__ bv,
    unsigned short* __restrict__ qo, unsigned short* __restrict__ ko,
    unsigned short* __restrict__ vo)
{
    __shared__ unsigned short sA[128 * 64];
    __shared__ unsigned short sB[128 * 64];
    const int tid = threadIdx.x;
    const int by = blockIdx.y;
    const int sel = by >> 2;
    const int n0 = (by & 3) * 128;
    const int m0 = blockIdx.x * 128;
    const unsigned short* W = sel == 0 ? Wq : (sel == 1 ? Wk : Wv);
    const float* bias = sel == 0 ? bq : (sel == 1 ? bk : bv);

    f32x4 acc[4][4];
    gemm128_core(x, W, m0, n0, tid, sA, sB, acc);

    const int lane = tid & 63, wid = tid >> 6;
    const int quad = lane >> 4, l15 = lane & 15;
    const int wm = wid >> 1, wn = wid & 1;
    float bv4[4];
    #pragma unroll
    for (int j = 0; j < 4; j++) bv4[j] = bias[n0 + wn * 64 + j * 16 + l15];

    if (sel == 2) {
        // V^T: [B,H,64,T]
        #pragma unroll
        for (int i = 0; i < 4; i++) {
            #pragma unroll
            for (int j = 0; j < 4; j++) {
                int n = n0 + wn * 64 + j * 16 + l15;
                int h = n >> 6, d = n & 63;
                int m = m0 + wm * 64 + i * 16 + quad * 4;
                int b = m >> 12, t = m & 4095;
                uint2 pk;
                pk.x = cvtpk(acc[i][j][0] + bv4[j], acc[i][j][1] + bv4[j]);
                pk.y = cvtpk(acc[i][j][2] + bv4[j], acc[i][j][3] + bv4[j]);
                *(uint2*)(vo + ((size_t)(b * 8 + h) * 64 + d) * 4096 + t) = pk;
            }
        }
    } else {
        const float SC = (sel == 0) ? 0.125f * 1.44269504088896f : 1.0f;
        unsigned short* dst = sel == 0 ? qo : ko;
        #pragma unroll
        for (int i = 0; i < 4; i++) {
            #pragma unroll
            for (int j = 0; j < 4; j++) {
                int n = n0 + wn * 64 + j * 16 + l15;
                int h = n >> 6, d = n & 63;
                int m = m0 + wm * 64 + i * 16 + quad * 4;
                int b = m >> 12, t = m & 4095;
                size_t base2 = ((size_t)(b * 8 + h) * 4096 + t) * 64 + d;
                unsigned p01 = cvtpk((acc[i][j][0] + bv4[j]) * SC,
                                     (acc[i][j][1] + bv4[j]) * SC);
                unsigned p23 = cvtpk((acc[i][j][2] + bv4[j]) * SC,
                                     (acc[i][j][3] + bv4[j]) * SC);
                dst[base2]       = (unsigned short)p01;
                dst[base2 + 64]  = (unsigned short)(p01 >> 16);
                dst[base2 + 128] = (unsigned short)p23;
                dst[base2 + 192] = (unsigned short)(p23 >> 16);
            }
        }
    }
}

// ---------------------------------------------------------------------------
// Flash attention, key-split. grid (32 q-tiles, 16 b*h), 512 threads = 2
// key-groups x 4 sub-waves; sub-wave owns 32 q rows. Q pre-scaled so
// p = exp2(s) directly. l-sums via ones-MFMA.
// P redistribution is IN-REGISTER (no sP LDS). Derivation:
//   S MFMA C-layout: lane(quad,l15) reg r = key rb*16+quad*4+r, query l15.
//   cvtpk pairs: X/Y = rbA keys {q*4+0,1}/{q*4+2,3}; Z/W = rbB.
//   PV B-frag needs keys half*32+quad*8+{0..7}:
//     word0 rows = [X.r0, X.r2, Z.r0, Z.r2], word2 = [X.r1, X.r3, Z.r1, Z.r3]
//   permlane32_swap(X,Z) -> s0=[X0,X1,Z0,Z1], s1=[X2,X3,Z2,Z3]
//   permlane16_swap(s0,s1) -> t0=[X0,X2,Z0,Z2]=word0, t1=[X1,X3,Z1,Z3]=word2.
// LDS = 32KB (K/V tiles only) + 512B lsum-combine.
// ---------------------------------------------------------------------------
__global__ __launch_bounds__(512, 4) void attn_kernel(
    const unsigned short* __restrict__ qg, const unsigned short* __restrict__ kg,
    const unsigned short* __restrict__ vtg, unsigned short* __restrict__ og)
{
    __shared__ unsigned char smem[33280];

    const int tid = threadIdx.x;
    const int lane = tid & 63;
    const int w = tid >> 6;          // wave 0..7
    const int g = tid >> 8;          // key-group 0,1
    const int gt = tid & 255;
    const int sw = w & 3;            // sub-wave in group
    const int quad = lane >> 4, l15 = lane & 15;
    const int bh = blockIdx.y;
    const size_t base = (size_t)bh * 4096 * 64;
    const unsigned short* Q = qg + base;
    const unsigned short* K = kg + base;
    const unsigned short* VT = vtg + base;   // [64 d][4096 t]
    const int qt0 = blockIdx.x * 128;

    unsigned short* sK  = (unsigned short*)(smem + g * 8192);          // [64 key][64 d]
    unsigned short* sVt = (unsigned short*)(smem + 16384 + g * 8192);  // [64 d][64 key]

    // Q fragments (B-operand of K.Q^T), persistent; Q pre-scaled in qkv
    bf16x8 qf[2][2];
    #pragma unroll
    for (int cb = 0; cb < 2; cb++) {
        int q = qt0 + sw * 32 + cb * 16 + l15;
        #pragma unroll
        for (int ks = 0; ks < 2; ks++)
            qf[cb][ks] = *(const bf16x8*)(Q + (size_t)q * 64 + ks * 32 + quad * 8);
    }

    f32x4 ot[4][2];
    #pragma unroll
    for (int i = 0; i < 4; i++)
        #pragma unroll
        for (int cb = 0; cb < 2; cb++) {
            f32x4 z = {0.f, 0.f, 0.f, 0.f};
            ot[i][cb] = z;
        }
    f32x4 ls[2];
    {
        f32x4 z = {0.f, 0.f, 0.f, 0.f};
        ls[0] = z; ls[1] = z;
    }
    const short one_b = (short)0x3F80;  // bf16 1.0
    const bf16x8 ones = {one_b, one_b, one_b, one_b, one_b, one_b, one_b, one_b};

    const int c0 = gt, c1 = gt + 256;
    const int r0 = c0 >> 3, kc0 = c0 & 7;
    const int r1 = c1 >> 3, kc1 = c1 & 7;

    // preload tile g*64
    uint4 kr0, kr1, vr0, vr1;
    {
        int kb = g * 64;
        kr0 = *(const uint4*)(K + (size_t)(kb + r0) * 64 + kc0 * 8);
        kr1 = *(const uint4*)(K + (size_t)(kb + r1) * 64 + kc1 * 8);
        vr0 = *(const uint4*)(VT + (size_t)r0 * 4096 + kb + kc0 * 8);
        vr1 = *(const uint4*)(VT + (size_t)r1 * 4096 + kb + kc1 * 8);
    }

    for (int it = 0; it < 32; it++) {
        // stage regs -> LDS
        *(uint4*)((char*)sK + r0 * 128 + ((kc0 ^ (r0 & 7)) << 4)) = kr0;
        *(uint4*)((char*)sK + r1 * 128 + ((kc1 ^ (r1 & 7)) << 4)) = kr1;
        *(uint4*)((char*)sVt + r0 * 128 + ((kc0 ^ (r0 & 7)) << 4)) = vr0;
        *(uint4*)((char*)sVt + r1 * 128 + ((kc1 ^ (r1 & 7)) << 4)) = vr1;
        __syncthreads();

        // deep prefetch of next tile into registers
        {
            int itn = (it < 31) ? it + 1 : it;
            int kbn = (2 * itn + g) * 64;
            kr0 = *(const uint4*)(K + (size_t)(kbn + r0) * 64 + kc0 * 8);
            kr1 = *(const uint4*)(K + (size_t)(kbn + r1) * 64 + kc1 * 8);
            vr0 = *(const uint4*)(VT + (size_t)r0 * 4096 + kbn + kc0 * 8);
            vr1 = *(const uint4*)(VT + (size_t)r1 * 4096 + kbn + kc1 * 8);
        }

        #pragma unroll
        for (int half = 0; half < 2; half++) {
            // S-phase half: rb = half*2 (A: x/y) and half*2+1 (B: z/w).
            // Per cb: x = cvtpk(p0,p1), y = cvtpk(p2,p3) of rbA; z,w of rbB.
            unsigned xA[2], yA[2], zB[2], wB[2];
            #pragma unroll
            for (int rb2 = 0; rb2 < 2; rb2++) {
                int rb = half * 2 + rb2;
                int row = rb * 16 + l15;
                f32x4 s0 = {0.f, 0.f, 0.f, 0.f};
                f32x4 s1 = {0.f, 0.f, 0.f, 0.f};
                __builtin_amdgcn_s_setprio(1);
                #pragma unroll
                for (int ks = 0; ks < 2; ks++) {
                    int kc = ks * 4 + quad;
                    bf16x8 ka = *(const bf16x8*)((const char*)sK + row * 128 + ((kc ^ (row & 7)) << 4));
                    s0 = MFMA(ka, qf[0][ks], s0);
                    s1 = MFMA(ka, qf[1][ks], s1);
                }
                __builtin_amdgcn_s_setprio(0);
                unsigned e0 = cvtpk(__builtin_amdgcn_exp2f(s0[0]),
                                    __builtin_amdgcn_exp2f(s0[1]));
                unsigned e1 = cvtpk(__builtin_amdgcn_exp2f(s0[2]),
                                    __builtin_amdgcn_exp2f(s0[3]));
                unsigned f0 = cvtpk(__builtin_amdgcn_exp2f(s1[0]),
                                    __builtin_amdgcn_exp2f(s1[1]));
                unsigned f1 = cvtpk(__builtin_amdgcn_exp2f(s1[2]),
                                    __builtin_amdgcn_exp2f(s1[3]));
                if (rb2 == 0) { xA[0] = e0; yA[0] = e1; xA[1] = f0; yA[1] = f1; }
                else          { zB[0] = e0; wB[0] = e1; zB[1] = f0; wB[1] = f1; }
            }

            // In-register P redistribution (see header comment for derivation)
            bf16x8 pf[2];
            #pragma unroll
            for (int cb = 0; cb < 2; cb++) {
                u32x2 s  = __builtin_amdgcn_permlane32_swap(xA[cb], zB[cb], false, false);
                u32x2 t  = __builtin_amdgcn_permlane16_swap(s[0], s[1], false, false);
                u32x2 s2 = __builtin_amdgcn_permlane32_swap(yA[cb], wB[cb], false, false);
                u32x2 t2 = __builtin_amdgcn_permlane16_swap(s2[0], s2[1], false, false);
                u32x4 fr = { t[0], t2[0], t[1], t2[1] };
                pf[cb] = __builtin_bit_cast(bf16x8, fr);
            }

            // PV half: ks2 = half; B-frag = pf (keys half*32 + quad*8 + {0..7})
            {
                int ks2 = half;
                __builtin_amdgcn_s_setprio(1);
                ls[0] = MFMA(ones, pf[0], ls[0]);
                ls[1] = MFMA(ones, pf[1], ls[1]);
                #pragma unroll
                for (int rbd = 0; rbd < 4; rbd++) {
                    int row = rbd * 16 + l15;
                    int kc = ks2 * 4 + quad;
                    bf16x8 vf = *(const bf16x8*)((const char*)sVt + row * 128 + ((kc ^ (row & 7)) << 4));
                    ot[rbd][0] = MFMA(vf, pf[0], ot[rbd][0]);
                    ot[rbd][1] = MFMA(vf, pf[1], ot[rbd][1]);
                }
                __builtin_amdgcn_s_setprio(0);
            }
        }
        __syncthreads();
    }

    // combine group partials via LDS (pure sums: fixed m=0 softmax)
    float* oc = (float*)smem;              // [128 q][64 d] f32, swizzled (32KB)
    float* lc = (float*)(smem + 32768);    // 128 floats
    if (g == 1) {
        #pragma unroll
        for (int cb = 0; cb < 2; cb++) {
            int qb = sw * 32 + cb * 16 + l15;
            if (quad == 0) lc[qb] = ls[cb][0];
            #pragma unroll
            for (int rbd = 0; rbd < 4; rbd++) {
                int dc = rbd * 4 + quad;
                *(f32x4*)((char*)oc + qb * 256 + ((dc ^ (qb & 15)) << 4)) = ot[rbd][cb];
            }
        }
    }
    __syncthreads();
    if (g == 0) {
        const int b = bh >> 3, h = bh & 7;
        #pragma unroll
        for (int cb = 0; cb < 2; cb++) {
            int qb = sw * 32 + cb * 16 + l15;
            float inv = 1.f / (ls[cb][0] + lc[qb]);
            int q = qt0 + qb;
            #pragma unroll
            for (int rbd = 0; rbd < 4; rbd++) {
                int dc = rbd * 4 + quad;
                f32x4 o2 = *(const f32x4*)((char*)oc + qb * 256 + ((dc ^ (qb & 15)) << 4));
                uint2 pk;
                pk.x = cvtpk((ot[rbd][cb][0] + o2[0]) * inv,
                             (ot[rbd][cb][1] + o2[1]) * inv);
                pk.y = cvtpk((ot[rbd][cb][2] + o2[2]) * inv,
                             (ot[rbd][cb][3] + o2[3]) * inv);
                *(uint2*)(og + ((size_t)(b * 4096 + q) * 512 + h * 64 + rbd * 16 + quad * 4)) = pk;
            }
        }
    }
}

// ---------------------------------------------------------------------------
// Output projection: out = attn[8192,512] @ Wo^T + bo -> float32 out
// ---------------------------------------------------------------------------
__global__ __launch_bounds__(256) void out_kernel(
    const unsigned short* __restrict__ attn,
    const unsigned short* __restrict__ Wo, const float* __restrict__ bo,
    float* __restrict__ out)
{
    __shared__ unsigned short sA[128 * 64];
    __shared__ unsigned short sB[128 * 64];
    const int tid = threadIdx.x;
    const int m0 = blockIdx.x * 128;
    const int n0 = blockIdx.y * 128;

    f32x4 acc[4][4];
    gemm128_core(attn, Wo, m0, n0, tid, sA, sB, acc);

    const int lane = tid & 63, wid = tid >> 6;
    const int quad = lane >> 4, l15 = lane & 15;
    const int wm = wid >> 1, wn = wid & 1;
    float bv4[4];
    #pragma unroll
    for (int j = 0; j < 4; j++) bv4[j] = bo[n0 + wn * 64 + j * 16 + l15];
    #pragma unroll
    for (int i = 0; i < 4; i++) {
        #pragma unroll
        for (int j = 0; j < 4; j++) {
            int n = n0 + wn * 64 + j * 16 + l15;
            #pragma unroll
            for (int r = 0; r < 4; r++) {
                int m = m0 + wm * 64 + i * 16 + quad * 4 + r;
                out[(size_t)m * 512 + n] = acc[i][j][r] + bv4[j];
            }
        }
    }
}

extern "C" void kernel_launch(void* const* d_in, const int* in_sizes, int n_in,
                              void* d_out, int out_size, void* d_ws, size_t ws_size,
                              hipStream_t stream) {
    const float* x  = (const float*)d_in[0];
    const float* Wq = (const float*)d_in[1];
    const float* bq = (const float*)d_in[2];
    const float* Wk = (const float*)d_in[3];
    const float* bk = (const float*)d_in[4];
    const float* Wv = (const float*)d_in[5];
    const float* bv = (const float*)d_in[6];
    const float* Wo = (const float*)d_in[7];
    const float* bo = (const float*)d_in[8];
    unsigned short* ws = (unsigned short*)d_ws;

    const size_t NTOK = (size_t)2 * 4096 * 512;
    const size_t WSZ = (size_t)512 * 512;
    unsigned short* xb  = ws;
    unsigned short* Wqb = ws + NTOK;
    unsigned short* Wkb = Wqb + WSZ;
    unsigned short* Wvb = Wkb + WSZ;
    unsigned short* Wob = Wvb + WSZ;
    unsigned short* q_ws = Wob + WSZ;   // [B,H,T,64] (pre-scaled)
    unsigned short* k_ws = q_ws + NTOK; // [B,H,T,64]
    unsigned short* v_ws = k_ws + NTOK; // [B,H,64,T]  (V^T)
    unsigned short* a_ws = v_ws + NTOK; // [B,T,512]

    cvt_kernel<<<5120, 256, 0, stream>>>(x, Wq, Wk, Wv, Wo, xb, Wqb, Wkb, Wvb, Wob);
    qkv_kernel<<<dim3(64, 12), 256, 0, stream>>>(xb, Wqb, bq, Wkb, bk, Wvb, bv,
                                                 q_ws, k_ws, v_ws);
    attn_kernel<<<dim3(32, 16), 512, 0, stream>>>(q_ws, k_ws, v_ws, a_ws);
    out_kernel<<<dim3(64, 4), 256, 0, stream>>>(a_ws, Wob, bo,
                                                (float*)d_out);
}

// Round 6
// 189.722 us; speedup vs baseline: 1.0558x; 1.0254x over previous
//
#include <hip/hip_runtime.h>

typedef short bf16x8 __attribute__((ext_vector_type(8)));
typedef float f32x4 __attribute__((ext_vector_type(4)));
typedef unsigned u32x2 __attribute__((ext_vector_type(2)));
typedef unsigned u32x4 __attribute__((ext_vector_type(4)));

#define MFMA(a, b, c) __builtin_amdgcn_mfma_f32_16x16x32_bf16((a), (b), (c), 0, 0, 0)

// hardware packed f32->bf16 (RNE): 1 instr replaces ~6 integer-ALU ops
__device__ __forceinline__ unsigned cvtpk(float a, float b) {
    unsigned r;
    asm("v_cvt_pk_bf16_f32 %0, %1, %2" : "=v"(r) : "v"(a), "v"(b));
    return r;
}

// async global->LDS, 16B per lane; LDS dest = wave-uniform base + lane*16
__device__ __forceinline__ void gload16(const void* g, void* l) {
    __builtin_amdgcn_global_load_lds(
        (const __attribute__((address_space(1))) unsigned*)g,
        (__attribute__((address_space(3))) unsigned*)l, 16, 0, 0);
}

// ---------------------------------------------------------------------------
// f32 -> bf16 convert (x: blocks 0..4095; W0..W3: 256 blocks each)
// ---------------------------------------------------------------------------
__global__ __launch_bounds__(256) void cvt_kernel(
    const float* __restrict__ x,
    const float* __restrict__ w0, const float* __restrict__ w1,
    const float* __restrict__ w2, const float* __restrict__ w3,
    unsigned short* __restrict__ xd,
    unsigned short* __restrict__ d0, unsigned short* __restrict__ d1,
    unsigned short* __restrict__ d2, unsigned short* __restrict__ d3)
{
    int bid = blockIdx.x;
    const float* src;
    unsigned short* dst;
    int off;
    if (bid < 4096) { src = x; dst = xd; off = bid; }
    else {
        int s = (bid - 4096) >> 8;
        src = s == 0 ? w0 : (s == 1 ? w1 : (s == 2 ? w2 : w3));
        dst = s == 0 ? d0 : (s == 1 ? d1 : (s == 2 ? d2 : d3));
        off = (bid - 4096) & 255;
    }
    size_t i = ((size_t)off * 256 + threadIdx.x) * 4;
    float4 v = *(const float4*)(src + i);
    uint2 pk;
    pk.x = cvtpk(v.x, v.y);
    pk.y = cvtpk(v.z, v.w);
    *(uint2*)(dst + i) = pk;
}

// ---------------------------------------------------------------------------
// 128x128 GEMM tile core: C = A[M,512] * W[512,512]^T (bf16, K-contiguous).
// Staging via global_load_lds (linear LDS dest, pre-swizzled global source):
// LDS[row][slot] = A[row][slot ^ (row&7)].
// ---------------------------------------------------------------------------
__device__ __forceinline__ void gemm128_core(
    const unsigned short* __restrict__ A, const unsigned short* __restrict__ W,
    int m0, int n0, int tid, unsigned short* sA, unsigned short* sB,
    f32x4 acc[4][4])
{
    const int lane = tid & 63, wid = tid >> 6;
    const int quad = lane >> 4, l15 = lane & 15;
    const int wm = wid >> 1, wn = wid & 1;

    // source swizzle for gload_lds: lane l covers dest byte chunk*1024+l*16
    // -> row = chunk*8 + (l>>3), slot = l&7, so src kc = (l&7)^(l>>3)
    const int gl_r = lane >> 3;               // 0..7 (== row&7)
    const int gl_kc = (lane & 7) ^ gl_r;      // source k-chunk

    #pragma unroll
    for (int i = 0; i < 4; i++)
        #pragma unroll
        for (int j = 0; j < 4; j++) {
            f32x4 z = {0.f, 0.f, 0.f, 0.f};
            acc[i][j] = z;
        }

    for (int k0 = 0; k0 < 512; k0 += 64) {
        #pragma unroll
        for (int p = 0; p < 4; p++) {
            int chunk = wid * 4 + p;          // 0..15
            int row = chunk * 8 + gl_r;       // 0..127
            gload16(A + (size_t)(m0 + row) * 512 + k0 + gl_kc * 8,
                    (char*)sA + chunk * 1024);
            gload16(W + (size_t)(n0 + row) * 512 + k0 + gl_kc * 8,
                    (char*)sB + chunk * 1024);
        }
        __syncthreads();
        #pragma unroll
        for (int ks = 0; ks < 2; ks++) {
            bf16x8 af[4], bfr[4];
            #pragma unroll
            for (int i = 0; i < 4; i++) {
                int row = wm * 64 + i * 16 + l15;
                int kc = ks * 4 + quad;
                af[i] = *(const bf16x8*)((const char*)sA + row * 128 + ((kc ^ (row & 7)) << 4));
            }
            #pragma unroll
            for (int j = 0; j < 4; j++) {
                int row = wn * 64 + j * 16 + l15;
                int kc = ks * 4 + quad;
                bfr[j] = *(const bf16x8*)((const char*)sB + row * 128 + ((kc ^ (row & 7)) << 4));
            }
            #pragma unroll
            for (int i = 0; i < 4; i++)
                #pragma unroll
                for (int j = 0; j < 4; j++)
                    acc[i][j] = MFMA(af[i], bfr[j], acc[i][j]);
        }
        __syncthreads();
    }
}

// ---------------------------------------------------------------------------
// QKV projection: grid (64, 12); sel = y>>2 (0=q,1=k,2=v), n-tile = y&3.
// q: head-major [B,H,T,64], PRE-SCALED by 0.125*log2(e) (softmax fold).
// k: head-major [B,H,T,64]. v: transposed [B,H,64,T].
// ---------------------------------------------------------------------------
__global__ __launch_bounds__(256) void qkv_kernel(
    const unsigned short* __restrict__ x,
    const unsigned short* __restrict__ Wq, const float* __restrict__ bq,
    const unsigned short* __restrict__ Wk, const float* __restrict__ bk,
    const unsigned short* __restrict__ Wv, const float* __restrict__ bv,
    unsigned short* __restrict__ qo, unsigned short* __restrict__ ko,
    unsigned short* __restrict__ vo)
{
    __shared__ unsigned short sA[128 * 64];
    __shared__ unsigned short sB[128 * 64];
    const int tid = threadIdx.x;
    const int by = blockIdx.y;
    const int sel = by >> 2;
    const int n0 = (by & 3) * 128;
    const int m0 = blockIdx.x * 128;
    const unsigned short* W = sel == 0 ? Wq : (sel == 1 ? Wk : Wv);
    const float* bias = sel == 0 ? bq : (sel == 1 ? bk : bv);

    f32x4 acc[4][4];
    gemm128_core(x, W, m0, n0, tid, sA, sB, acc);

    const int lane = tid & 63, wid = tid >> 6;
    const int quad = lane >> 4, l15 = lane & 15;
    const int wm = wid >> 1, wn = wid & 1;
    float bv4[4];
    #pragma unroll
    for (int j = 0; j < 4; j++) bv4[j] = bias[n0 + wn * 64 + j * 16 + l15];

    if (sel == 2) {
        // V^T: [B,H,64,T]
        #pragma unroll
        for (int i = 0; i < 4; i++) {
            #pragma unroll
            for (int j = 0; j < 4; j++) {
                int n = n0 + wn * 64 + j * 16 + l15;
                int h = n >> 6, d = n & 63;
                int m = m0 + wm * 64 + i * 16 + quad * 4;
                int b = m >> 12, t = m & 4095;
                uint2 pk;
                pk.x = cvtpk(acc[i][j][0] + bv4[j], acc[i][j][1] + bv4[j]);
                pk.y = cvtpk(acc[i][j][2] + bv4[j], acc[i][j][3] + bv4[j]);
                *(uint2*)(vo + ((size_t)(b * 8 + h) * 64 + d) * 4096 + t) = pk;
            }
        }
    } else {
        const float SC = (sel == 0) ? 0.125f * 1.44269504088896f : 1.0f;
        unsigned short* dst = sel == 0 ? qo : ko;
        #pragma unroll
        for (int i = 0; i < 4; i++) {
            #pragma unroll
            for (int j = 0; j < 4; j++) {
                int n = n0 + wn * 64 + j * 16 + l15;
                int h = n >> 6, d = n & 63;
                int m = m0 + wm * 64 + i * 16 + quad * 4;
                int b = m >> 12, t = m & 4095;
                size_t base2 = ((size_t)(b * 8 + h) * 4096 + t) * 64 + d;
                unsigned p01 = cvtpk((acc[i][j][0] + bv4[j]) * SC,
                                     (acc[i][j][1] + bv4[j]) * SC);
                unsigned p23 = cvtpk((acc[i][j][2] + bv4[j]) * SC,
                                     (acc[i][j][3] + bv4[j]) * SC);
                dst[base2]       = (unsigned short)p01;
                dst[base2 + 64]  = (unsigned short)(p01 >> 16);
                dst[base2 + 128] = (unsigned short)p23;
                dst[base2 + 192] = (unsigned short)(p23 >> 16);
            }
        }
    }
}

// ---------------------------------------------------------------------------
// Flash attention, key-split. grid (32 q-tiles, 16 b*h), 512 threads = 2
// key-groups x 4 sub-waves; sub-wave owns 32 q rows. Q pre-scaled so
// p = exp2(s) directly. l-sums via ones-MFMA. In-register P redistribution
// (permlane32_swap + permlane16_swap on cvtpk pairs; see derivation below).
//
// K/V staging: DOUBLE-BUFFERED via global_load_lds (linear LDS dest,
// pre-swizzled source; LDS[row][slot] = src[row][slot^(row&7)]).
// ONE barrier per iter: vmcnt(0) -> barrier -> issue next-tile async loads
// -> compute current buffer. Safety: barrier at iter t guarantees all waves
// finished iter t-1 compute before any wave overwrites buf^1; per-wave
// vmcnt(0) before the barrier drains each wave's own staging loads.
//
// P derivation: S MFMA C-layout: lane(quad,l15) reg r = key rb*16+quad*4+r.
//   cvtpk pairs: X/Y = rbA keys {q*4+0,1}/{q*4+2,3}; Z/W = rbB.
//   permlane32_swap(X,Z) -> s0=[X0,X1,Z0,Z1], s1=[X2,X3,Z2,Z3]
//   permlane16_swap(s0,s1) -> t0=[X0,X2,Z0,Z2]=word0, t1=[X1,X3,Z1,Z3]=word2.
// LDS = 2 x 32KB K/V buffers + 512B lsum; combine area reuses buf0.
// ---------------------------------------------------------------------------
__global__ __launch_bounds__(512, 4) void attn_kernel(
    const unsigned short* __restrict__ qg, const unsigned short* __restrict__ kg,
    const unsigned short* __restrict__ vtg, unsigned short* __restrict__ og)
{
    __shared__ unsigned char smem[66048];

    const int tid = threadIdx.x;
    const int lane = tid & 63;
    const int w = tid >> 6;          // wave 0..7
    const int g = tid >> 8;          // key-group 0,1
    const int wg = w & 3;            // wave in group
    const int sw = w & 3;            // sub-wave in group
    const int quad = lane >> 4, l15 = lane & 15;
    const int bh = blockIdx.y;
    const size_t base = (size_t)bh * 4096 * 64;
    const unsigned short* Q = qg + base;
    const unsigned short* K = kg + base;
    const unsigned short* VT = vtg + base;   // [64 d][4096 t]
    const int qt0 = blockIdx.x * 128;

    // staging source swizzle (see gemm128_core)
    const int srow = lane >> 3;              // 0..7
    const int skc  = (lane & 7) ^ srow;      // source k-chunk

    // Q fragments (B-operand of K.Q^T), persistent; Q pre-scaled in qkv
    bf16x8 qf[2][2];
    #pragma unroll
    for (int cb = 0; cb < 2; cb++) {
        int q = qt0 + sw * 32 + cb * 16 + l15;
        #pragma unroll
        for (int ks = 0; ks < 2; ks++)
            qf[cb][ks] = *(const bf16x8*)(Q + (size_t)q * 64 + ks * 32 + quad * 8);
    }

    f32x4 ot[4][2];
    #pragma unroll
    for (int i = 0; i < 4; i++)
        #pragma unroll
        for (int cb = 0; cb < 2; cb++) {
            f32x4 z = {0.f, 0.f, 0.f, 0.f};
            ot[i][cb] = z;
        }
    f32x4 ls[2];
    {
        f32x4 z = {0.f, 0.f, 0.f, 0.f};
        ls[0] = z; ls[1] = z;
    }
    const short one_b = (short)0x3F80;  // bf16 1.0
    const bf16x8 ones = {one_b, one_b, one_b, one_b, one_b, one_b, one_b, one_b};

    // prologue: stage tile 0 into buf 0
    {
        int kb = g * 64;
        unsigned char* bK = smem + g * 8192;
        unsigned char* bV = smem + 16384 + g * 8192;
        #pragma unroll
        for (int p = 0; p < 2; p++) {
            int chunk = wg * 2 + p;          // 0..7
            int row = chunk * 8 + srow;      // 0..63
            gload16(K + (size_t)(kb + row) * 64 + skc * 8, bK + chunk * 1024);
            gload16(VT + (size_t)row * 4096 + kb + skc * 8, bV + chunk * 1024);
        }
    }

    int buf = 0;
    for (int it = 0; it < 32; it++) {
        __asm__ __volatile__("s_waitcnt vmcnt(0)" ::: "memory");
        __syncthreads();

        // issue next tile's async staging into the other buffer
        if (it < 31) {
            int kb = (2 * (it + 1) + g) * 64;
            unsigned char* bK = smem + (buf ^ 1) * 32768 + g * 8192;
            unsigned char* bV = smem + (buf ^ 1) * 32768 + 16384 + g * 8192;
            #pragma unroll
            for (int p = 0; p < 2; p++) {
                int chunk = wg * 2 + p;
                int row = chunk * 8 + srow;
                gload16(K + (size_t)(kb + row) * 64 + skc * 8, bK + chunk * 1024);
                gload16(VT + (size_t)row * 4096 + kb + skc * 8, bV + chunk * 1024);
            }
        }

        unsigned short* sK  = (unsigned short*)(smem + buf * 32768 + g * 8192);
        unsigned short* sVt = (unsigned short*)(smem + buf * 32768 + 16384 + g * 8192);

        #pragma unroll
        for (int half = 0; half < 2; half++) {
            // S-phase half: rb = half*2 (A: x/y) and half*2+1 (B: z/w).
            unsigned xA[2], yA[2], zB[2], wB[2];
            #pragma unroll
            for (int rb2 = 0; rb2 < 2; rb2++) {
                int rb = half * 2 + rb2;
                int row = rb * 16 + l15;
                f32x4 s0 = {0.f, 0.f, 0.f, 0.f};
                f32x4 s1 = {0.f, 0.f, 0.f, 0.f};
                __builtin_amdgcn_s_setprio(1);
                #pragma unroll
                for (int ks = 0; ks < 2; ks++) {
                    int kc = ks * 4 + quad;
                    bf16x8 ka = *(const bf16x8*)((const char*)sK + row * 128 + ((kc ^ (row & 7)) << 4));
                    s0 = MFMA(ka, qf[0][ks], s0);
                    s1 = MFMA(ka, qf[1][ks], s1);
                }
                __builtin_amdgcn_s_setprio(0);
                unsigned e0 = cvtpk(__builtin_amdgcn_exp2f(s0[0]),
                                    __builtin_amdgcn_exp2f(s0[1]));
                unsigned e1 = cvtpk(__builtin_amdgcn_exp2f(s0[2]),
                                    __builtin_amdgcn_exp2f(s0[3]));
                unsigned f0 = cvtpk(__builtin_amdgcn_exp2f(s1[0]),
                                    __builtin_amdgcn_exp2f(s1[1]));
                unsigned f1 = cvtpk(__builtin_amdgcn_exp2f(s1[2]),
                                    __builtin_amdgcn_exp2f(s1[3]));
                if (rb2 == 0) { xA[0] = e0; yA[0] = e1; xA[1] = f0; yA[1] = f1; }
                else          { zB[0] = e0; wB[0] = e1; zB[1] = f0; wB[1] = f1; }
            }

            // In-register P redistribution (see header comment)
            bf16x8 pf[2];
            #pragma unroll
            for (int cb = 0; cb < 2; cb++) {
                u32x2 s  = __builtin_amdgcn_permlane32_swap(xA[cb], zB[cb], false, false);
                u32x2 t  = __builtin_amdgcn_permlane16_swap(s[0], s[1], false, false);
                u32x2 s2 = __builtin_amdgcn_permlane32_swap(yA[cb], wB[cb], false, false);
                u32x2 t2 = __builtin_amdgcn_permlane16_swap(s2[0], s2[1], false, false);
                u32x4 fr = { t[0], t2[0], t[1], t2[1] };
                pf[cb] = __builtin_bit_cast(bf16x8, fr);
            }

            // PV half: ks2 = half; B-frag = pf (keys half*32 + quad*8 + {0..7})
            {
                int ks2 = half;
                __builtin_amdgcn_s_setprio(1);
                ls[0] = MFMA(ones, pf[0], ls[0]);
                ls[1] = MFMA(ones, pf[1], ls[1]);
                #pragma unroll
                for (int rbd = 0; rbd < 4; rbd++) {
                    int row = rbd * 16 + l15;
                    int kc = ks2 * 4 + quad;
                    bf16x8 vf = *(const bf16x8*)((const char*)sVt + row * 128 + ((kc ^ (row & 7)) << 4));
                    ot[rbd][0] = MFMA(vf, pf[0], ot[rbd][0]);
                    ot[rbd][1] = MFMA(vf, pf[1], ot[rbd][1]);
                }
                __builtin_amdgcn_s_setprio(0);
            }
        }
        buf ^= 1;
    }

    // combine group partials via LDS (pure sums: fixed m=0 softmax).
    // Last compute read buf1 (smem[32768..65536)); oc uses buf0 region — no
    // overlap with any wave still finishing iter 31. lc lives past buf1.
    float* oc = (float*)smem;              // [128 q][64 d] f32, swizzled (32KB)
    float* lc = (float*)(smem + 65536);    // 128 floats
    if (g == 1) {
        #pragma unroll
        for (int cb = 0; cb < 2; cb++) {
            int qb = sw * 32 + cb * 16 + l15;
            if (quad == 0) lc[qb] = ls[cb][0];
            #pragma unroll
            for (int rbd = 0; rbd < 4; rbd++) {
                int dc = rbd * 4 + quad;
                *(f32x4*)((char*)oc + qb * 256 + ((dc ^ (qb & 15)) << 4)) = ot[rbd][cb];
            }
        }
    }
    __syncthreads();
    if (g == 0) {
        const int b = bh >> 3, h = bh & 7;
        #pragma unroll
        for (int cb = 0; cb < 2; cb++) {
            int qb = sw * 32 + cb * 16 + l15;
            float inv = 1.f / (ls[cb][0] + lc[qb]);
            int q = qt0 + qb;
            #pragma unroll
            for (int rbd = 0; rbd < 4; rbd++) {
                int dc = rbd * 4 + quad;
                f32x4 o2 = *(const f32x4*)((char*)oc + qb * 256 + ((dc ^ (qb & 15)) << 4));
                uint2 pk;
                pk.x = cvtpk((ot[rbd][cb][0] + o2[0]) * inv,
                             (ot[rbd][cb][1] + o2[1]) * inv);
                pk.y = cvtpk((ot[rbd][cb][2] + o2[2]) * inv,
                             (ot[rbd][cb][3] + o2[3]) * inv);
                *(uint2*)(og + ((size_t)(b * 4096 + q) * 512 + h * 64 + rbd * 16 + quad * 4)) = pk;
            }
        }
    }
}

// ---------------------------------------------------------------------------
// Output projection: out = attn[8192,512] @ Wo^T + bo -> float32 out
// ---------------------------------------------------------------------------
__global__ __launch_bounds__(256) void out_kernel(
    const unsigned short* __restrict__ attn,
    const unsigned short* __restrict__ Wo, const float* __restrict__ bo,
    float* __restrict__ out)
{
    __shared__ unsigned short sA[128 * 64];
    __shared__ unsigned short sB[128 * 64];
    const int tid = threadIdx.x;
    const int m0 = blockIdx.x * 128;
    const int n0 = blockIdx.y * 128;

    f32x4 acc[4][4];
    gemm128_core(attn, Wo, m0, n0, tid, sA, sB, acc);

    const int lane = tid & 63, wid = tid >> 6;
    const int quad = lane >> 4, l15 = lane & 15;
    const int wm = wid >> 1, wn = wid & 1;
    float bv4[4];
    #pragma unroll
    for (int j = 0; j < 4; j++) bv4[j] = bo[n0 + wn * 64 + j * 16 + l15];
    #pragma unroll
    for (int i = 0; i < 4; i++) {
        #pragma unroll
        for (int j = 0; j < 4; j++) {
            int n = n0 + wn * 64 + j * 16 + l15;
            #pragma unroll
            for (int r = 0; r < 4; r++) {
                int m = m0 + wm * 64 + i * 16 + quad * 4 + r;
                out[(size_t)m * 512 + n] = acc[i][j][r] + bv4[j];
            }
        }
    }
}

extern "C" void kernel_launch(void* const* d_in, const int* in_sizes, int n_in,
                              void* d_out, int out_size, void* d_ws, size_t ws_size,
                              hipStream_t stream) {
    const float* x  = (const float*)d_in[0];
    const float* Wq = (const float*)d_in[1];
    const float* bq = (const float*)d_in[2];
    const float* Wk = (const float*)d_in[3];
    const float* bk = (const float*)d_in[4];
    const float* Wv = (const float*)d_in[5];
    const float* bv = (const float*)d_in[6];
    const float* Wo = (const float*)d_in[7];
    const float* bo = (const float*)d_in[8];
    unsigned short* ws = (unsigned short*)d_ws;

    const size_t NTOK = (size_t)2 * 4096 * 512;
    const size_t WSZ = (size_t)512 * 512;
    unsigned short* xb  = ws;
    unsigned short* Wqb = ws + NTOK;
    unsigned short* Wkb = Wqb + WSZ;
    unsigned short* Wvb = Wkb + WSZ;
    unsigned short* Wob = Wvb + WSZ;
    unsigned short* q_ws = Wob + WSZ;   // [B,H,T,64] (pre-scaled)
    unsigned short* k_ws = q_ws + NTOK; // [B,H,T,64]
    unsigned short* v_ws = k_ws + NTOK; // [B,H,64,T]  (V^T)
    unsigned short* a_ws = v_ws + NTOK; // [B,T,512]

    cvt_kernel<<<5120, 256, 0, stream>>>(x, Wq, Wk, Wv, Wo, xb, Wqb, Wkb, Wvb, Wob);
    qkv_kernel<<<dim3(64, 12), 256, 0, stream>>>(xb, Wqb, bq, Wkb, bk, Wvb, bv,
                                                 q_ws, k_ws, v_ws);
    attn_kernel<<<dim3(32, 16), 512, 0, stream>>>(q_ws, k_ws, v_ws, a_ws);
    out_kernel<<<dim3(64, 4), 256, 0, stream>>>(a_ws, Wob, bo,
                                                (float*)d_out);
}